// Round 3
// baseline (214.890 us; speedup 1.0000x reference)
//
#include <hip/hip_runtime.h>

// Problem constants: B=4, L=2048, C=64, D=4
#define BB 4
#define LL 2048
#define KK 256   // a-chains per batch = C*D; each thread owns the 4 j-subchains of one a-chain

// Layout (verified, round-2 kernel passed with it):
//  A flat idx   (b,t,c,i)   = (b*L+t)*256 + k          where k = c*4+i
//  X float4 idx (b,t,k)     = (b*L+t)*256 + k          (re and im separately)
//  out float4   (b,t,k)     = 2*((b*L+t)*256 + k) + {0,1}   ([y_re0,y_im0,y_re1,y_im1], [..2,..3])

// ---------------- Phase 1: per-(b,g,k) chunk aggregates ----------------
// p = prod of A over chunk; s_j = chunk-local scan result of X_j (zero seed).
template<int G, int LOGG>
__global__ __launch_bounds__(256, 4) void pscan_phase1(
    const float* __restrict__ A_re, const float* __restrict__ A_im,
    const float4* __restrict__ X4_re, const float4* __restrict__ X4_im,
    float2* __restrict__ agg_p, float4* __restrict__ agg_s) {
  constexpr int T = LL / G;
  int u  = blockIdx.x * 256 + threadIdx.x;   // [0, BB*G*KK)
  int k  = u & (KK - 1);
  int bg = u >> 8;                           // b*G + g
  int g  = bg & (G - 1);
  int b  = bg >> LOGG;
  long base = (long)(b * LL + g * T) * KK + k;

  float p_re = 1.f, p_im = 0.f;
  float s_re[4] = {0.f, 0.f, 0.f, 0.f};
  float s_im[4] = {0.f, 0.f, 0.f, 0.f};
#pragma unroll
  for (int t = 0; t < T; ++t) {
    long idx = base + (long)t * KK;
    float are = A_re[idx], aim = A_im[idx];
    float4 xr = X4_re[idx], xi = X4_im[idx];
    float xrv[4] = {xr.x, xr.y, xr.z, xr.w};
    float xiv[4] = {xi.x, xi.y, xi.z, xi.w};
#pragma unroll
    for (int j = 0; j < 4; ++j) {
      float nr = fmaf(are, s_re[j], fmaf(-aim, s_im[j], xrv[j]));
      float ni = fmaf(are, s_im[j], fmaf( aim, s_re[j], xiv[j]));
      s_re[j] = nr; s_im[j] = ni;
    }
    float npr = are * p_re - aim * p_im;
    float npi = are * p_im + aim * p_re;
    p_re = npr; p_im = npi;
  }
  agg_p[u]       = make_float2(p_re, p_im);
  agg_s[2*u]     = make_float4(s_re[0], s_im[0], s_re[1], s_im[1]);
  agg_s[2*u + 1] = make_float4(s_re[2], s_im[2], s_re[3], s_im[3]);
}

// ---------------- Phase 2: exclusive scan of aggregates over g, in place ----------------
// One thread per chain (b,k): 1024 threads, coalesced loads/stores each g-step.
// Running prefix only needs s (combine uses the CHUNK's p, never the prefix's p).
template<int G>
__global__ __launch_bounds__(256) void pscan_phase2(
    const float2* __restrict__ agg_p, float4* __restrict__ agg_s) {
  int u = blockIdx.x * 256 + threadIdx.x;    // [0, BB*KK)
  int k = u & (KK - 1);
  int b = u >> 8;
  float rs_re[4] = {0.f, 0.f, 0.f, 0.f};
  float rs_im[4] = {0.f, 0.f, 0.f, 0.f};
#pragma unroll 4
  for (int g = 0; g < G; ++g) {
    long idx = (long)(b * G + g) * KK + k;
    float2 p   = agg_p[idx];
    float4 s01 = agg_s[2*idx];
    float4 s23 = agg_s[2*idx + 1];
    // write exclusive prefix (value BEFORE absorbing this chunk)
    agg_s[2*idx]     = make_float4(rs_re[0], rs_im[0], rs_re[1], rs_im[1]);
    agg_s[2*idx + 1] = make_float4(rs_re[2], rs_im[2], rs_re[3], rs_im[3]);
    float svr[4] = {s01.x, s01.z, s23.x, s23.z};
    float svi[4] = {s01.y, s01.w, s23.y, s23.w};
#pragma unroll
    for (int j = 0; j < 4; ++j) {
      float nr = fmaf(p.x, rs_re[j], fmaf(-p.y, rs_im[j], svr[j]));
      float ni = fmaf(p.x, rs_im[j], fmaf( p.y, rs_re[j], svi[j]));
      rs_re[j] = nr; rs_im[j] = ni;
    }
  }
}

// ---------------- Phase 3: seed with carry, re-run recurrence, write out ----------------
template<int G, int LOGG>
__global__ __launch_bounds__(256, 4) void pscan_phase3(
    const float* __restrict__ A_re, const float* __restrict__ A_im,
    const float4* __restrict__ X4_re, const float4* __restrict__ X4_im,
    const float4* __restrict__ agg_s, float4* __restrict__ out4) {
  constexpr int T = LL / G;
  int u  = blockIdx.x * 256 + threadIdx.x;
  int k  = u & (KK - 1);
  int bg = u >> 8;
  int g  = bg & (G - 1);
  int b  = bg >> LOGG;
  long base = (long)(b * LL + g * T) * KK + k;

  float4 c01 = agg_s[2*u], c23 = agg_s[2*u + 1];
  float yr[4] = {c01.x, c01.z, c23.x, c23.z};
  float yi[4] = {c01.y, c01.w, c23.y, c23.w};
#pragma unroll
  for (int t = 0; t < T; ++t) {
    long idx = base + (long)t * KK;
    float are = A_re[idx], aim = A_im[idx];
    float4 xr = X4_re[idx], xi = X4_im[idx];
    float xrv[4] = {xr.x, xr.y, xr.z, xr.w};
    float xiv[4] = {xi.x, xi.y, xi.z, xi.w};
#pragma unroll
    for (int j = 0; j < 4; ++j) {
      float nr = fmaf(are, yr[j], fmaf(-aim, yi[j], xrv[j]));
      float ni = fmaf(are, yi[j], fmaf( aim, yr[j], xiv[j]));
      yr[j] = nr; yi[j] = ni;
    }
    out4[2*idx]     = make_float4(yr[0], yi[0], yr[1], yi[1]);
    out4[2*idx + 1] = make_float4(yr[2], yi[2], yr[3], yi[3]);
  }
}

template<int G, int LOGG>
static void launch_all(const float* A_re, const float* A_im,
                       const float4* X4_re, const float4* X4_im,
                       void* d_ws, float4* out4, hipStream_t stream) {
  float2* agg_p = (float2*)d_ws;
  float4* agg_s = (float4*)((char*)d_ws + (size_t)BB * G * KK * sizeof(float2));
  int blocks = BB * G;   // (BB*G*KK)/256 with KK=256
  pscan_phase1<G, LOGG><<<blocks, 256, 0, stream>>>(A_re, A_im, X4_re, X4_im, agg_p, agg_s);
  pscan_phase2<G><<<(BB * KK) / 256, 256, 0, stream>>>(agg_p, agg_s);
  pscan_phase3<G, LOGG><<<blocks, 256, 0, stream>>>(A_re, A_im, X4_re, X4_im, agg_s, out4);
}

extern "C" void kernel_launch(void* const* d_in, const int* in_sizes, int n_in,
                              void* d_out, int out_size, void* d_ws, size_t ws_size,
                              hipStream_t stream) {
  const float*  A_re  = (const float*)d_in[0];
  const float*  A_im  = (const float*)d_in[1];
  const float4* X4_re = (const float4*)d_in[2];
  const float4* X4_im = (const float4*)d_in[3];
  float4* out4 = (float4*)d_out;

  // Workspace need: BB*G*KK*(8 + 32) bytes. G=256 -> 10.5 MB (ws is 256 MiB per
  // the harness's observed poison fills). Fall back to G=64 (2.6 MB) if tight.
  const size_t need256 = (size_t)BB * 256 * KK * (sizeof(float2) + 2 * sizeof(float4));
  if (ws_size >= need256) {
    launch_all<256, 8>(A_re, A_im, X4_re, X4_im, d_ws, out4, stream);
  } else {
    launch_all<64, 6>(A_re, A_im, X4_re, X4_im, d_ws, out4, stream);
  }
}

// Round 5
// 172.113 us; speedup vs baseline: 1.2485x; 1.2485x over previous
//
#include <hip/hip_runtime.h>

// Problem constants: B=4, L=2048, C=64, D=4
#define BB 4
#define LL 2048
#define KK 256   // a-chains per batch = C*D; thread owns the 4 j-subchains of one a-chain
#define GG 256   // time chunks
#define TT (LL / GG)   // 8 steps per chunk

// Native 4-float vector for nontemporal builtins (HIP's float4 is a struct).
typedef float nfloat4 __attribute__((ext_vector_type(4)));

// Layout (verified across rounds 1-3):
//  A flat idx   (b,t,c,i)   = (b*L+t)*256 + k          where k = c*4+i
//  X float4 idx (b,t,k)     = (b*L+t)*256 + k          (re and im separately)
//  out float4   (b,t,k)     = 2*((b*L+t)*256 + k) + {0,1}

// ---------------- Phase 1: per-(b,g,k) chunk aggregates ----------------
__global__ __launch_bounds__(256, 4) void pscan_phase1(
    const float* __restrict__ A_re, const float* __restrict__ A_im,
    const float4* __restrict__ X4_re, const float4* __restrict__ X4_im,
    float2* __restrict__ agg_p, float4* __restrict__ agg_s) {
  int u  = blockIdx.x * 256 + threadIdx.x;   // [0, BB*GG*KK)
  int k  = u & (KK - 1);
  int bg = u >> 8;                           // b*GG + g
  int g  = bg & (GG - 1);
  int b  = bg >> 8;
  long base = (long)(b * LL + g * TT) * KK + k;

  float p_re = 1.f, p_im = 0.f;
  float s_re[4] = {0.f, 0.f, 0.f, 0.f};
  float s_im[4] = {0.f, 0.f, 0.f, 0.f};
#pragma unroll
  for (int t = 0; t < TT; ++t) {
    long idx = base + (long)t * KK;
    float are = A_re[idx], aim = A_im[idx];
    float4 xr = X4_re[idx], xi = X4_im[idx];
    float xrv[4] = {xr.x, xr.y, xr.z, xr.w};
    float xiv[4] = {xi.x, xi.y, xi.z, xi.w};
#pragma unroll
    for (int j = 0; j < 4; ++j) {
      float nr = fmaf(are, s_re[j], fmaf(-aim, s_im[j], xrv[j]));
      float ni = fmaf(are, s_im[j], fmaf( aim, s_re[j], xiv[j]));
      s_re[j] = nr; s_im[j] = ni;
    }
    float npr = are * p_re - aim * p_im;
    float npi = are * p_im + aim * p_re;
    p_re = npr; p_im = npi;
  }
  agg_p[u]       = make_float2(p_re, p_im);
  agg_s[2*u]     = make_float4(s_re[0], s_im[0], s_re[1], s_im[1]);
  agg_s[2*u + 1] = make_float4(s_re[2], s_im[2], s_re[3], s_im[3]);
}

// ---------------- Phase 2: block-per-chain exclusive scan over g ----------------
// 1024 blocks (one per (b,k) chain), 256 threads = one per chunk g.
// Wave-level Hillis-Steele shuffle scan + LDS cross-wave combine. In-place on agg_s.
// combine(L earlier, R later): s = p_R*s_L + s_R ; p = p_R*p_L
__global__ __launch_bounds__(256) void pscan_phase2(
    const float2* __restrict__ agg_p, float4* __restrict__ agg_s) {
  __shared__ float lds_p[4][2];
  __shared__ float lds_s[4][8];
  int chain = blockIdx.x;              // [0, BB*KK)
  int b = chain >> 8, k = chain & (KK - 1);
  int g = threadIdx.x;
  int w = g >> 6, l = g & 63;
  long idx = (long)(b * GG + g) * KK + k;

  float2 p   = agg_p[idx];
  float4 s01 = agg_s[2*idx], s23 = agg_s[2*idx + 1];
  float pr = p.x, pi = p.y;
  float sr[4] = {s01.x, s01.z, s23.x, s23.z};
  float si[4] = {s01.y, s01.w, s23.y, s23.w};

  // inclusive scan within the wave
#pragma unroll
  for (int d = 1; d < 64; d <<= 1) {
    float plr = __shfl_up(pr, d, 64);
    float pli = __shfl_up(pi, d, 64);
    float slr[4], sli[4];
#pragma unroll
    for (int j = 0; j < 4; ++j) {
      slr[j] = __shfl_up(sr[j], d, 64);
      sli[j] = __shfl_up(si[j], d, 64);
    }
    if (l >= d) {
#pragma unroll
      for (int j = 0; j < 4; ++j) {
        float nr = fmaf(pr, slr[j], fmaf(-pi, sli[j], sr[j]));
        float ni = fmaf(pr, sli[j], fmaf( pi, slr[j], si[j]));
        sr[j] = nr; si[j] = ni;
      }
      float npr = pr * plr - pi * pli;
      float npi = pr * pli + pi * plr;
      pr = npr; pi = npi;
    }
  }

  // wave-local exclusive
  float epr = __shfl_up(pr, 1, 64), epi = __shfl_up(pi, 1, 64);
  float esr[4], esi[4];
#pragma unroll
  for (int j = 0; j < 4; ++j) {
    esr[j] = __shfl_up(sr[j], 1, 64);
    esi[j] = __shfl_up(si[j], 1, 64);
  }
  if (l == 0) {
    epr = 1.f; epi = 0.f;
#pragma unroll
    for (int j = 0; j < 4; ++j) { esr[j] = 0.f; esi[j] = 0.f; }
  }

  // wave totals -> LDS
  if (l == 63) {
    lds_p[w][0] = pr; lds_p[w][1] = pi;
#pragma unroll
    for (int j = 0; j < 4; ++j) { lds_s[w][2*j] = sr[j]; lds_s[w][2*j+1] = si[j]; }
  }
  __syncthreads();

  // prefix over earlier waves (<=3 combines, every thread computes its own)
  float wpr = 1.f, wpi = 0.f;
  float wsr[4] = {0.f,0.f,0.f,0.f}, wsi[4] = {0.f,0.f,0.f,0.f};
  for (int ww = 0; ww < w; ++ww) {
    float tpr = lds_p[ww][0], tpi = lds_p[ww][1];
#pragma unroll
    for (int j = 0; j < 4; ++j) {
      float tsr = lds_s[ww][2*j], tsi = lds_s[ww][2*j+1];
      float nr = fmaf(tpr, wsr[j], fmaf(-tpi, wsi[j], tsr));
      float ni = fmaf(tpr, wsi[j], fmaf( tpi, wsr[j], tsi));
      wsr[j] = nr; wsi[j] = ni;
    }
    float npr = tpr * wpr - tpi * wpi;
    float npi = tpr * wpi + tpi * wpr;
    wpr = npr; wpi = npi;
  }

  // seed for chunk g = combine(wave_prefix, wave_local_exclusive) — s-part only
  float seedr[4], seedi[4];
#pragma unroll
  for (int j = 0; j < 4; ++j) {
    seedr[j] = fmaf(epr, wsr[j], fmaf(-epi, wsi[j], esr[j]));
    seedi[j] = fmaf(epr, wsi[j], fmaf( epi, wsr[j], esi[j]));
  }
  agg_s[2*idx]     = make_float4(seedr[0], seedi[0], seedr[1], seedi[1]);
  agg_s[2*idx + 1] = make_float4(seedr[2], seedi[2], seedr[3], seedi[3]);
}

// ---------------- Phase 3: seed with carry, re-run recurrence, write out ----------------
__global__ __launch_bounds__(256, 4) void pscan_phase3(
    const float* __restrict__ A_re, const float* __restrict__ A_im,
    const float4* __restrict__ X4_re, const float4* __restrict__ X4_im,
    const float4* __restrict__ agg_s, nfloat4* __restrict__ out4) {
  int u  = blockIdx.x * 256 + threadIdx.x;
  int k  = u & (KK - 1);
  int bg = u >> 8;
  int g  = bg & (GG - 1);
  int b  = bg >> 8;
  long base = (long)(b * LL + g * TT) * KK + k;

  float4 c01 = agg_s[2*u], c23 = agg_s[2*u + 1];
  float yr[4] = {c01.x, c01.z, c23.x, c23.z};
  float yi[4] = {c01.y, c01.w, c23.y, c23.w};
#pragma unroll
  for (int t = 0; t < TT; ++t) {
    long idx = base + (long)t * KK;
    float are = A_re[idx], aim = A_im[idx];
    float4 xr = X4_re[idx], xi = X4_im[idx];
    float xrv[4] = {xr.x, xr.y, xr.z, xr.w};
    float xiv[4] = {xi.x, xi.y, xi.z, xi.w};
#pragma unroll
    for (int j = 0; j < 4; ++j) {
      float nr = fmaf(are, yr[j], fmaf(-aim, yi[j], xrv[j]));
      float ni = fmaf(are, yi[j], fmaf( aim, yr[j], xiv[j]));
      yr[j] = nr; yi[j] = ni;
    }
    // output is never re-read: nontemporal keeps L2/L3 warm for the A/X stream
    nfloat4 o0 = {yr[0], yi[0], yr[1], yi[1]};
    nfloat4 o1 = {yr[2], yi[2], yr[3], yi[3]};
    __builtin_nontemporal_store(o0, &out4[2*idx]);
    __builtin_nontemporal_store(o1, &out4[2*idx + 1]);
  }
}

extern "C" void kernel_launch(void* const* d_in, const int* in_sizes, int n_in,
                              void* d_out, int out_size, void* d_ws, size_t ws_size,
                              hipStream_t stream) {
  const float*  A_re  = (const float*)d_in[0];
  const float*  A_im  = (const float*)d_in[1];
  const float4* X4_re = (const float4*)d_in[2];
  const float4* X4_im = (const float4*)d_in[3];
  nfloat4* out4 = (nfloat4*)d_out;

  float2* agg_p = (float2*)d_ws;                                       // 2 MB
  float4* agg_s = (float4*)((char*)d_ws + (size_t)BB * GG * KK * sizeof(float2)); // 8 MB

  const int blocks = BB * GG;    // 1024
  pscan_phase1<<<blocks, 256, 0, stream>>>(A_re, A_im, X4_re, X4_im, agg_p, agg_s);
  pscan_phase2<<<BB * KK, 256, 0, stream>>>(agg_p, agg_s);
  pscan_phase3<<<blocks, 256, 0, stream>>>(A_re, A_im, X4_re, X4_im, agg_s, out4);
}

// Round 6
// 159.801 us; speedup vs baseline: 1.3447x; 1.0770x over previous
//
#include <hip/hip_runtime.h>

// Problem constants: B=4, L=2048, C=64, D=4
#define BB 4
#define LL 2048
#define KK 256   // a-chains per batch = C*D; thread owns the 4 j-subchains of one a-chain
#define GG 256   // time chunks
#define TT (LL / GG)   // 8 steps per chunk

// Layout (verified across rounds 1-5):
//  A flat idx   (b,t,c,i)   = (b*L+t)*256 + k          where k = c*4+i
//  X float4 idx (b,t,k)     = (b*L+t)*256 + k          (re and im separately)
//  out float4   (b,t,k)     = 2*((b*L+t)*256 + k) + {0,1}

// ---------------- Phase 1: per-(b,g,k) chunk aggregates ----------------
// Load-all-then-compute: issue all 32 loads (320 B/thread) before the dependent
// FMA chain, so the memory system sees deep MLP (round-5 VGPR=36 showed the
// compiler wasn't hoisting on its own; 3.8 TB/s latency-bound).
__global__ __launch_bounds__(256, 4) void pscan_phase1(
    const float* __restrict__ A_re, const float* __restrict__ A_im,
    const float4* __restrict__ X4_re, const float4* __restrict__ X4_im,
    float2* __restrict__ agg_p, float4* __restrict__ agg_s) {
  int u  = blockIdx.x * 256 + threadIdx.x;   // [0, BB*GG*KK)
  int k  = u & (KK - 1);
  int bg = u >> 8;                           // b*GG + g
  int g  = bg & (GG - 1);
  int b  = bg >> 8;
  long base = (long)(b * LL + g * TT) * KK + k;

  float  ar[TT], ai[TT];
  float4 xr[TT], xi[TT];
#pragma unroll
  for (int t = 0; t < TT; ++t) {
    long idx = base + (long)t * KK;
    ar[t] = A_re[idx];
    ai[t] = A_im[idx];
    xr[t] = X4_re[idx];
    xi[t] = X4_im[idx];
  }

  float p_re = 1.f, p_im = 0.f;
  float s_re[4] = {0.f, 0.f, 0.f, 0.f};
  float s_im[4] = {0.f, 0.f, 0.f, 0.f};
#pragma unroll
  for (int t = 0; t < TT; ++t) {
    float are = ar[t], aim = ai[t];
    float xrv[4] = {xr[t].x, xr[t].y, xr[t].z, xr[t].w};
    float xiv[4] = {xi[t].x, xi[t].y, xi[t].z, xi[t].w};
#pragma unroll
    for (int j = 0; j < 4; ++j) {
      float nr = fmaf(are, s_re[j], fmaf(-aim, s_im[j], xrv[j]));
      float ni = fmaf(are, s_im[j], fmaf( aim, s_re[j], xiv[j]));
      s_re[j] = nr; s_im[j] = ni;
    }
    float npr = are * p_re - aim * p_im;
    float npi = are * p_im + aim * p_re;
    p_re = npr; p_im = npi;
  }
  agg_p[u]       = make_float2(p_re, p_im);
  agg_s[2*u]     = make_float4(s_re[0], s_im[0], s_re[1], s_im[1]);
  agg_s[2*u + 1] = make_float4(s_re[2], s_im[2], s_re[3], s_im[3]);
}

// ---------------- Phase 2: block-per-chain exclusive scan over g ----------------
// (unchanged from round 5 — validated, fast)
__global__ __launch_bounds__(256) void pscan_phase2(
    const float2* __restrict__ agg_p, float4* __restrict__ agg_s) {
  __shared__ float lds_p[4][2];
  __shared__ float lds_s[4][8];
  int chain = blockIdx.x;              // [0, BB*KK)
  int b = chain >> 8, k = chain & (KK - 1);
  int g = threadIdx.x;
  int w = g >> 6, l = g & 63;
  long idx = (long)(b * GG + g) * KK + k;

  float2 p   = agg_p[idx];
  float4 s01 = agg_s[2*idx], s23 = agg_s[2*idx + 1];
  float pr = p.x, pi = p.y;
  float sr[4] = {s01.x, s01.z, s23.x, s23.z};
  float si[4] = {s01.y, s01.w, s23.y, s23.w};

#pragma unroll
  for (int d = 1; d < 64; d <<= 1) {
    float plr = __shfl_up(pr, d, 64);
    float pli = __shfl_up(pi, d, 64);
    float slr[4], sli[4];
#pragma unroll
    for (int j = 0; j < 4; ++j) {
      slr[j] = __shfl_up(sr[j], d, 64);
      sli[j] = __shfl_up(si[j], d, 64);
    }
    if (l >= d) {
#pragma unroll
      for (int j = 0; j < 4; ++j) {
        float nr = fmaf(pr, slr[j], fmaf(-pi, sli[j], sr[j]));
        float ni = fmaf(pr, sli[j], fmaf( pi, slr[j], si[j]));
        sr[j] = nr; si[j] = ni;
      }
      float npr = pr * plr - pi * pli;
      float npi = pr * pli + pi * plr;
      pr = npr; pi = npi;
    }
  }

  float epr = __shfl_up(pr, 1, 64), epi = __shfl_up(pi, 1, 64);
  float esr[4], esi[4];
#pragma unroll
  for (int j = 0; j < 4; ++j) {
    esr[j] = __shfl_up(sr[j], 1, 64);
    esi[j] = __shfl_up(si[j], 1, 64);
  }
  if (l == 0) {
    epr = 1.f; epi = 0.f;
#pragma unroll
    for (int j = 0; j < 4; ++j) { esr[j] = 0.f; esi[j] = 0.f; }
  }

  if (l == 63) {
    lds_p[w][0] = pr; lds_p[w][1] = pi;
#pragma unroll
    for (int j = 0; j < 4; ++j) { lds_s[w][2*j] = sr[j]; lds_s[w][2*j+1] = si[j]; }
  }
  __syncthreads();

  float wpr = 1.f, wpi = 0.f;
  float wsr[4] = {0.f,0.f,0.f,0.f}, wsi[4] = {0.f,0.f,0.f,0.f};
  for (int ww = 0; ww < w; ++ww) {
    float tpr = lds_p[ww][0], tpi = lds_p[ww][1];
#pragma unroll
    for (int j = 0; j < 4; ++j) {
      float tsr = lds_s[ww][2*j], tsi = lds_s[ww][2*j+1];
      float nr = fmaf(tpr, wsr[j], fmaf(-tpi, wsi[j], tsr));
      float ni = fmaf(tpr, wsi[j], fmaf( tpi, wsr[j], tsi));
      wsr[j] = nr; wsi[j] = ni;
    }
    float npr = tpr * wpr - tpi * wpi;
    float npi = tpr * wpi + tpi * wpr;
    wpr = npr; wpi = npi;
  }

  float seedr[4], seedi[4];
#pragma unroll
  for (int j = 0; j < 4; ++j) {
    seedr[j] = fmaf(epr, wsr[j], fmaf(-epi, wsi[j], esr[j]));
    seedi[j] = fmaf(epr, wsi[j], fmaf( epi, wsr[j], esi[j]));
  }
  agg_s[2*idx]     = make_float4(seedr[0], seedi[0], seedr[1], seedi[1]);
  agg_s[2*idx + 1] = make_float4(seedr[2], seedi[2], seedr[3], seedi[3]);
}

// ---------------- Phase 3: seed with carry, re-run recurrence, write out ----------------
// Plain stores (round-5 nontemporal stores caused 1.7x write amplification:
// each nt instruction writes 16B/lane at 32B stride -> half-covered sectors
// bypassing L2 merge; WRITE_SIZE 114 MB vs 67 MB ideal).
__global__ __launch_bounds__(256, 4) void pscan_phase3(
    const float* __restrict__ A_re, const float* __restrict__ A_im,
    const float4* __restrict__ X4_re, const float4* __restrict__ X4_im,
    const float4* __restrict__ agg_s, float4* __restrict__ out4) {
  int u  = blockIdx.x * 256 + threadIdx.x;
  int k  = u & (KK - 1);
  int bg = u >> 8;
  int g  = bg & (GG - 1);
  int b  = bg >> 8;
  long base = (long)(b * LL + g * TT) * KK + k;

  float  ar[TT], ai[TT];
  float4 xr[TT], xi[TT];
#pragma unroll
  for (int t = 0; t < TT; ++t) {
    long idx = base + (long)t * KK;
    ar[t] = A_re[idx];
    ai[t] = A_im[idx];
    xr[t] = X4_re[idx];
    xi[t] = X4_im[idx];
  }

  float4 c01 = agg_s[2*u], c23 = agg_s[2*u + 1];
  float yr[4] = {c01.x, c01.z, c23.x, c23.z};
  float yi[4] = {c01.y, c01.w, c23.y, c23.w};
#pragma unroll
  for (int t = 0; t < TT; ++t) {
    float are = ar[t], aim = ai[t];
    float xrv[4] = {xr[t].x, xr[t].y, xr[t].z, xr[t].w};
    float xiv[4] = {xi[t].x, xi[t].y, xi[t].z, xi[t].w};
#pragma unroll
    for (int j = 0; j < 4; ++j) {
      float nr = fmaf(are, yr[j], fmaf(-aim, yi[j], xrv[j]));
      float ni = fmaf(are, yi[j], fmaf( aim, yr[j], xiv[j]));
      yr[j] = nr; yi[j] = ni;
    }
    long idx = base + (long)t * KK;
    out4[2*idx]     = make_float4(yr[0], yi[0], yr[1], yi[1]);
    out4[2*idx + 1] = make_float4(yr[2], yi[2], yr[3], yi[3]);
  }
}

extern "C" void kernel_launch(void* const* d_in, const int* in_sizes, int n_in,
                              void* d_out, int out_size, void* d_ws, size_t ws_size,
                              hipStream_t stream) {
  const float*  A_re  = (const float*)d_in[0];
  const float*  A_im  = (const float*)d_in[1];
  const float4* X4_re = (const float4*)d_in[2];
  const float4* X4_im = (const float4*)d_in[3];
  float4* out4 = (float4*)d_out;

  float2* agg_p = (float2*)d_ws;                                       // 2 MB
  float4* agg_s = (float4*)((char*)d_ws + (size_t)BB * GG * KK * sizeof(float2)); // 8 MB

  const int blocks = BB * GG;    // 1024
  pscan_phase1<<<blocks, 256, 0, stream>>>(A_re, A_im, X4_re, X4_im, agg_p, agg_s);
  pscan_phase2<<<BB * KK, 256, 0, stream>>>(agg_p, agg_s);
  pscan_phase3<<<blocks, 256, 0, stream>>>(A_re, A_im, X4_re, X4_im, agg_s, out4);
}